// Round 1
// baseline (214.853 us; speedup 1.0000x reference)
//
#include <hip/hip_runtime.h>

#define TT 1024
#define BB 4096

// quad_perm DPP: broadcast within 4-lane groups (pure VALU, no LDS)
template<int CTRL>
__device__ __forceinline__ float qperm(float v) {
    int i = __builtin_bit_cast(int, v);
    i = __builtin_amdgcn_mov_dpp(i, CTRL, 0xF, 0xF, true);
    return __builtin_bit_cast(float, i);
}

__global__ void zero_loss_k(float* p) { *p = 0.0f; }

// 4 lanes per batch element: lane j owns hidden unit j. 16 elements/wave.
// 256 blocks x 64 threads -> 1 wave per CU across all 256 CUs.
__launch_bounds__(64, 1)
__global__ void bkt_rnn_k(const float* __restrict__ x,
                          const float* __restrict__ y,
                          const float* __restrict__ prior,
                          const float* __restrict__ W_ih,
                          const float* __restrict__ W_hh,
                          const float* __restrict__ b_ih,
                          const float* __restrict__ b_hh,
                          float* __restrict__ out)
{
    const int lane = threadIdx.x;
    const int j    = lane & 3;                      // hidden unit
    const int e    = blockIdx.x * 16 + (lane >> 2); // batch element

    // Fold 2*log2(e) into weights so tanh(z) = 1 - 2/(exp2(z')+1), z' = S*z
    const float S = 2.8853900817779268f; // 2*log2(e)
    // weights in xor-broadcast order: wk multiplies h_{j^k}
    const float w0 = S * W_hh[j * 4 + (j ^ 0)];
    const float w1 = S * W_hh[j * 4 + (j ^ 1)];
    const float w2 = S * W_hh[j * 4 + (j ^ 2)];
    const float w3 = S * W_hh[j * 4 + (j ^ 3)];
    const float bsum = b_ih[j] + b_hh[j];
    const float c0 = S * bsum;             // x == 0
    const float c1 = S * (bsum + W_ih[j]); // x == 1

    const float p0 = prior[0];
    float latent = 1.0f / (1.0f + __builtin_amdgcn_exp2f(-1.4426950408889634f * p0));

    const float* xp = x + e;
    const float* yp = y + e;
    float* cOut = out + e;
    float* lOut = out + (size_t)TT * BB + e;

    float hq0 = 0.f, hq1 = 0.f, hq2 = 0.f, hq3 = 0.f; // broadcast h (prev step)
    float lossAcc = 0.f;

    constexpr int U  = 8;       // steps per prefetch group
    constexpr int NG = TT / U;  // 128 groups
    float xA[U], yA[U], xB[U], yB[U];

    #pragma unroll
    for (int u = 0; u < U; ++u) { xA[u] = xp[(size_t)u * BB]; yA[u] = yp[(size_t)u * BB]; }

    auto step = [&](float xv, float yv, int t) {
        // RNN: z' = S*(W_hh h + b + x*W_ih), per-lane unit j
        float z = (xv != 0.0f) ? c1 : c0;
        z = fmaf(hq0, w0, z);
        z = fmaf(hq1, w1, z);
        z = fmaf(hq2, w2, z);
        z = fmaf(hq3, w3, z);
        float ex = __builtin_amdgcn_exp2f(z);
        float r  = __builtin_amdgcn_rcpf(ex + 1.0f);
        float h  = fmaf(-2.0f, r, 1.0f); // tanh
        // broadcast within quad; on lane j, hq_k = h_{j^k}
        hq0 = h;
        hq1 = qperm<0xB1>(h); // quad_perm [1,0,3,2]
        hq2 = qperm<0x4E>(h); // quad_perm [2,3,0,1]
        hq3 = qperm<0x1B>(h); // quad_perm [3,2,1,0]
        // BKT (valid on lane j==0 where hq_k = h_k): params p = (h+1)/2
        //   correct     = latent*(1-s-g) + g = latent*(-(hs+hg)/2) + (hg+1)/2
        //   next_latent = latent*(1-f-l) + l = 0.5*(hl + 1 - latent*(hf+hl))   [m_t == latent exactly]
        float gg2  = fmaf(0.5f, hq2, 0.5f);
        float u2   = hq3 + hq2;
        float corr = fmaf(latent, -0.5f * u2, gg2);
        float u1   = hq1 + hq0;
        float nl   = fmaf(0.5f, fmaf(-latent, u1, hq0), 0.5f);
        // BCE: y in {0,1} exactly
        float lp = (yv != 0.0f) ? corr : (1.0f - corr);
        float lg = 0.6931471805599453f * __builtin_amdgcn_logf(lp); // ln
        lg = fmaxf(lg, -100.0f);
        lossAcc += lg;
        if (j == 0) {
            cOut[(size_t)t * BB] = corr;
            lOut[(size_t)t * BB] = nl;
        }
        latent = nl;
    };

    for (int gg = 0; gg < NG / 2; ++gg) {
        const int gB = 2 * gg + 1; // always < NG
        #pragma unroll
        for (int u = 0; u < U; ++u) {
            xB[u] = xp[(size_t)(gB * U + u) * BB];
            yB[u] = yp[(size_t)(gB * U + u) * BB];
        }
        const int tA = 2 * gg * U;
        #pragma unroll
        for (int u = 0; u < U; ++u) step(xA[u], yA[u], tA + u);

        const int gA = (2 * gg + 2 < NG) ? (2 * gg + 2) : (NG - 1); // clamp last (unused data)
        #pragma unroll
        for (int u = 0; u < U; ++u) {
            xA[u] = xp[(size_t)(gA * U + u) * BB];
            yA[u] = yp[(size_t)(gA * U + u) * BB];
        }
        #pragma unroll
        for (int u = 0; u < U; ++u) step(xB[u], yB[u], gB * U + u);
    }

    // loss: sum valid lane contributions (j==0), wave butterfly reduce, one atomic/block
    float v = (j == 0) ? lossAcc : 0.0f;
    #pragma unroll
    for (int o = 32; o >= 1; o >>= 1) v += __shfl_xor(v, o, 64);
    if (lane == 0) {
        atomicAdd(out + 2 * (size_t)TT * BB, v * (-1.0f / ((float)TT * (float)BB)));
    }
}

extern "C" void kernel_launch(void* const* d_in, const int* in_sizes, int n_in,
                              void* d_out, int out_size, void* d_ws, size_t ws_size,
                              hipStream_t stream) {
    const float* x    = (const float*)d_in[0];
    const float* y    = (const float*)d_in[1];
    const float* pr   = (const float*)d_in[2];
    const float* W_ih = (const float*)d_in[3];
    const float* W_hh = (const float*)d_in[4];
    const float* b_ih = (const float*)d_in[5];
    const float* b_hh = (const float*)d_in[6];
    float* out = (float*)d_out;

    zero_loss_k<<<1, 1, 0, stream>>>(out + 2 * (size_t)TT * BB);
    bkt_rnn_k<<<BB / 16, 64, 0, stream>>>(x, y, pr, W_ih, W_hh, b_ih, b_hh, out);
}